// Round 6
// baseline (511.244 us; speedup 1.0000x reference)
//
#include <hip/hip_runtime.h>
#include <hip/hip_bf16.h>

#define S_LEN 2048
#define NH 16
#define HD 64
#define DM 1024

typedef float f32x4 __attribute__((ext_vector_type(4)));
typedef unsigned u32x4 __attribute__((ext_vector_type(4)));
typedef __bf16 bf16x8 __attribute__((ext_vector_type(8)));

__device__ __forceinline__ unsigned short f2bf(float f) {
  union { float f; unsigned u; } v; v.f = f;
  unsigned r = v.u + 0x7fffu + ((v.u >> 16) & 1u);
  return (unsigned short)(r >> 16);
}

__device__ __forceinline__ unsigned pack2bf(float lo, float hi) {
  return (unsigned)f2bf(lo) | ((unsigned)f2bf(hi) << 16);
}

__device__ __forceinline__ void load_lds16(const void* g, void* l) {
  __builtin_amdgcn_global_load_lds((const __attribute__((address_space(1))) void*)g,
                                   (__attribute__((address_space(3))) void*)l, 16, 0, 0);
}

// fp32 -> bf16 rowmajor convert (4 elems/thread)
__global__ __launch_bounds__(256) void cvt_kernel(const float* __restrict__ in,
                                                  unsigned short* __restrict__ out) {
  int i = blockIdx.x * 256 + threadIdx.x;
  float4 v = reinterpret_cast<const float4*>(in)[i];
  ushort4 o;
  o.x = f2bf(v.x); o.y = f2bf(v.y); o.z = f2bf(v.z); o.w = f2bf(v.w);
  reinterpret_cast<ushort4*>(out)[i] = o;
}

// W [1024][1024] fp32 -> Wt [n][k] bf16 (transpose + convert)
__global__ __launch_bounds__(256) void wtrans_kernel(const float* __restrict__ W,
                                                     unsigned short* __restrict__ Wt) {
  __shared__ float t[32][33];
  int bx = blockIdx.x * 32;  // n base
  int by = blockIdx.y * 32;  // k base
  int tx = threadIdx.x & 31, ty = threadIdx.x >> 5;
  for (int i = ty; i < 32; i += 8) t[i][tx] = W[(size_t)(by + i) * DM + bx + tx];
  __syncthreads();
  for (int i = ty; i < 32; i += 8) Wt[(size_t)(bx + i) * DM + by + tx] = f2bf(t[tx][i]);
}

// C = A[4096x1024] @ Bt[1024x1024]^T + bias.  128x128 tile, BK=32, 4 waves.
// MODE 0: bf16 head-major out [B,H,S,64]; MODE 1: bf16 transposed [B,H,64,S]; MODE 2: fp32 rowmajor.
template <int MODE>
__global__ __launch_bounds__(256) void gemm128(const unsigned short* __restrict__ A,
                                               const unsigned short* __restrict__ Bt,
                                               const float* __restrict__ bias,
                                               void* __restrict__ outp) {
  constexpr int K = 1024;
  constexpr int N = 1024;
  __shared__ unsigned short Al[128 * 32];
  __shared__ unsigned short Bl[128 * 32];
  const int tid = threadIdx.x;
  const int w = tid >> 6, l = tid & 63;
  const int m0 = blockIdx.x * 128, n0 = blockIdx.y * 128;
  const int wr = (w >> 1) * 64, wc = (w & 1) * 64;
  const int lr = l & 15, lk = l >> 4;
  f32x4 acc[4][4] = {};
  for (int kt = 0; kt < K; kt += 32) {
#pragma unroll
    for (int i = 0; i < 2; ++i) {
      int seg = i * 256 + tid;
      int row = seg >> 2, ks = (seg & 3) * 8;
      load_lds16(A + (size_t)(m0 + row) * K + kt + ks, Al + seg * 8);
      load_lds16(Bt + (size_t)(n0 + row) * K + kt + ks, Bl + seg * 8);
    }
    __syncthreads();
    bf16x8 af[4], bfr[4];
#pragma unroll
    for (int t = 0; t < 4; ++t) af[t] = *(const bf16x8*)(Al + (wr + t * 16 + lr) * 32 + lk * 8);
#pragma unroll
    for (int t = 0; t < 4; ++t) bfr[t] = *(const bf16x8*)(Bl + (wc + t * 16 + lr) * 32 + lk * 8);
#pragma unroll
    for (int i = 0; i < 4; ++i)
#pragma unroll
      for (int j = 0; j < 4; ++j)
        acc[i][j] = __builtin_amdgcn_mfma_f32_16x16x32_bf16(af[i], bfr[j], acc[i][j], 0, 0, 0);
    __syncthreads();
  }
  const int drow = lk * 4, dcol = lr;
  if (MODE == 2) {
    float* C = (float*)outp;
#pragma unroll
    for (int i = 0; i < 4; ++i)
#pragma unroll
      for (int j = 0; j < 4; ++j) {
        int n = n0 + wc + j * 16 + dcol;
        float bv = bias[n];
#pragma unroll
        for (int r = 0; r < 4; ++r) {
          int m = m0 + wr + i * 16 + drow + r;
          C[(size_t)m * N + n] = acc[i][j][r] + bv;
        }
      }
  } else if (MODE == 0) {
    unsigned short* C = (unsigned short*)outp;
#pragma unroll
    for (int i = 0; i < 4; ++i)
#pragma unroll
      for (int j = 0; j < 4; ++j) {
        int n = n0 + wc + j * 16 + dcol;
        float bv = bias[n];
        int h = n >> 6, d = n & 63;
#pragma unroll
        for (int r = 0; r < 4; ++r) {
          int m = m0 + wr + i * 16 + drow + r;
          int b = m >> 11, s = m & 2047;
          C[((size_t)(b * NH + h) * S_LEN + s) * HD + d] = f2bf(acc[i][j][r] + bv);
        }
      }
  } else {  // MODE 1: V transposed [B,H,64,S]
    unsigned short* C = (unsigned short*)outp;
#pragma unroll
    for (int i = 0; i < 4; ++i) {
      int m = m0 + wr + i * 16 + drow;  // rows m..m+3 same b (16-aligned)
      int b = m >> 11, s = m & 2047;
#pragma unroll
      for (int j = 0; j < 4; ++j) {
        int n = n0 + wc + j * 16 + dcol;
        float bv = bias[n];
        int h = n >> 6, d = n & 63;
        ushort4 o;
        o.x = f2bf(acc[i][j][0] + bv);
        o.y = f2bf(acc[i][j][1] + bv);
        o.z = f2bf(acc[i][j][2] + bv);
        o.w = f2bf(acc[i][j][3] + bv);
        *reinterpret_cast<ushort4*>(C + ((size_t)(b * NH + h) * HD + d) * S_LEN + s) = o;
      }
    }
  }
}

// ---------------------------------------------------------------------------
// Two-pass flash-style fused attention.
// Block = 512 threads (8 waves); wave w owns q-rows [q0w, q0w+16) for the FULL
// k=2048 -> softmax is wave-local (no block barriers, no LDS). Pass 1: stream K
// in register ping-pong tiles of 64 k, online max/sum. Pass 2: recompute QK,
// p = exp(s - m - log(l)), non-temporal attn store, inline PV via the verified
// shfl P-remap; ctx written directly per wave.
// Swapped MFMA (A=K, B=Q): lane (lr,lk) holds S[k=T*64+t4*16+lk*4+r][q=q0w+lr].
// ---------------------------------------------------------------------------
#define LK(BUF, T)                                                                       \
  _Pragma("unroll") for (int t4 = 0; t4 < 4; ++t4) {                                     \
    const unsigned short* kp = Kbh + (size_t)((T) * 64 + t4 * 16 + lr) * HD + lk * 8;    \
    BUF[t4][0] = *(const bf16x8*)kp;                                                     \
    BUF[t4][1] = *(const bf16x8*)(kp + 32);                                              \
  }

#define QKT(BUF)                                                                         \
  _Pragma("unroll") for (int t4 = 0; t4 < 4; ++t4) {                                     \
    f32x4 a = {};                                                                        \
    a = __builtin_amdgcn_mfma_f32_16x16x32_bf16(BUF[t4][0], qf0, a, 0, 0, 0);            \
    a = __builtin_amdgcn_mfma_f32_16x16x32_bf16(BUF[t4][1], qf1, a, 0, 0, 0);            \
    acc[t4] = a;                                                                         \
  }

#define MASKADJ(T)                                                                       \
  _Pragma("unroll") for (int t4 = 0; t4 < 4; ++t4) {                                     \
    uchar4 m4 = *(const uchar4*)(mrow + (T) * 64 + t4 * 16 + lk * 4);                    \
    if (m4.x) acc[t4][0] = -8e9f;                                                        \
    if (m4.y) acc[t4][1] = -8e9f;                                                        \
    if (m4.z) acc[t4][2] = -8e9f;                                                        \
    if (m4.w) acc[t4][3] = -8e9f;                                                        \
  }

#define P1(BUF, T)                                                                       \
  {                                                                                      \
    u32x4 mv = *(const u32x4*)(mrow + (T) * 64 + lk * 16);                               \
    int am = __any((mv.x | mv.y | mv.z | mv.w) != 0);                                    \
    QKT(BUF)                                                                             \
    if (am) {                                                                            \
      maskbits |= 1u << (T);                                                             \
      MASKADJ(T)                                                                         \
    }                                                                                    \
    float tm = -3e38f;                                                                   \
    _Pragma("unroll") for (int t4 = 0; t4 < 4; ++t4)                                     \
      _Pragma("unroll") for (int r = 0; r < 4; ++r) {                                    \
        float v = acc[t4][r] * sc;                                                       \
        acc[t4][r] = v;                                                                  \
        tm = fmaxf(tm, v);                                                               \
      }                                                                                  \
    tm = fmaxf(tm, __shfl_xor(tm, 16, 64));                                              \
    tm = fmaxf(tm, __shfl_xor(tm, 32, 64));                                              \
    float mn = fmaxf(m, tm);                                                             \
    float ts = 0.f;                                                                      \
    _Pragma("unroll") for (int t4 = 0; t4 < 4; ++t4)                                     \
      _Pragma("unroll") for (int r = 0; r < 4; ++r) ts += __expf(acc[t4][r] - mn);       \
    lsum = lsum * __expf(m - mn) + ts;                                                   \
    m = mn;                                                                              \
  }

#define P2(BUF, T)                                                                       \
  {                                                                                      \
    QKT(BUF)                                                                             \
    if (maskbits & (1u << (T))) { MASKADJ(T) }                                           \
    unsigned pk0[4], pk1[4];                                                             \
    _Pragma("unroll") for (int t4 = 0; t4 < 4; ++t4) {                                   \
      f32x4 o;                                                                           \
      o.x = __expf(acc[t4][0] * sc - m2);                                                \
      o.y = __expf(acc[t4][1] * sc - m2);                                                \
      o.z = __expf(acc[t4][2] * sc - m2);                                                \
      o.w = __expf(acc[t4][3] * sc - m2);                                                \
      __builtin_nontemporal_store(o, (f32x4*)(arow + (T) * 64 + t4 * 16 + lk * 4));      \
      pk0[t4] = pack2bf(o.x, o.y);                                                       \
      pk1[t4] = pack2bf(o.z, o.w);                                                       \
    }                                                                                    \
    _Pragma("unroll") for (int ks = 0; ks < 2; ++ks) {                                   \
      bf16x8 vb[4];                                                                      \
      _Pragma("unroll") for (int dt = 0; dt < 4; ++dt)                                   \
        vb[dt] = *(const bf16x8*)(Vbh + (size_t)(dt * 16 + lr) * S_LEN + (T) * 64 + ks * 32 + lk * 8); \
      unsigned x0a = __shfl(pk0[2 * ks], srcA, 64), x0b = __shfl(pk0[2 * ks + 1], srcA, 64); \
      unsigned x1a = __shfl(pk1[2 * ks], srcA, 64), x1b = __shfl(pk1[2 * ks + 1], srcA, 64); \
      unsigned x2a = __shfl(pk0[2 * ks], srcB, 64), x2b = __shfl(pk0[2 * ks + 1], srcB, 64); \
      unsigned x3a = __shfl(pk1[2 * ks], srcB, 64), x3b = __shfl(pk1[2 * ks + 1], srcB, 64); \
      union { unsigned u[4]; bf16x8 v; } af;                                             \
      af.u[0] = hi ? x0b : x0a;                                                          \
      af.u[1] = hi ? x1b : x1a;                                                          \
      af.u[2] = hi ? x2b : x2a;                                                          \
      af.u[3] = hi ? x3b : x3a;                                                          \
      _Pragma("unroll") for (int dt = 0; dt < 4; ++dt)                                   \
        cacc[dt] = __builtin_amdgcn_mfma_f32_16x16x32_bf16(af.v, vb[dt], cacc[dt], 0, 0, 0); \
    }                                                                                    \
  }

__global__ __launch_bounds__(512, 4) void attn2_kernel(const unsigned short* __restrict__ Qh,
                                                       const unsigned short* __restrict__ Kh,
                                                       const unsigned short* __restrict__ Vt,
                                                       const unsigned char* __restrict__ mask,
                                                       float* __restrict__ attn_out,
                                                       unsigned short* __restrict__ ctx) {
  const int tid = threadIdx.x;
  const int w = tid >> 6, l = tid & 63;
  const int lr = l & 15, lk = l >> 4;
  const int q0w = blockIdx.x * 128 + w * 16;
  const int bh = blockIdx.y;
  const int b = bh >> 4, h = bh & 15;
  const unsigned short* Qbh = Qh + (size_t)bh * S_LEN * HD;
  const unsigned short* Kbh = Kh + (size_t)bh * S_LEN * HD;
  const unsigned short* Vbh = Vt + (size_t)bh * HD * S_LEN;
  const unsigned char* mrow = mask + (size_t)b * S_LEN * S_LEN + (size_t)(q0w + lr) * S_LEN;
  float* arow = attn_out + ((size_t)bh * S_LEN + q0w + lr) * S_LEN;

  bf16x8 qf0 = *(const bf16x8*)(Qbh + (q0w + lr) * HD + lk * 8);
  bf16x8 qf1 = *(const bf16x8*)(Qbh + (q0w + lr) * HD + 32 + lk * 8);

  const float sc = 0.125f;  // 1/sqrt(64)
  float m = -3e38f, lsum = 0.f;
  unsigned maskbits = 0;
  f32x4 acc[4];
  bf16x8 kA[4][2], kB[4][2];

  // ---- pass 1: online max/sum over all k ----
  LK(kA, 0)
  for (int t = 0; t < 32; t += 2) {
    LK(kB, t + 1)
    P1(kA, t)
    LK(kA, (t + 2) & 31)  // last iter harmlessly reloads tile 0
    P1(kB, t + 1)
  }
  lsum += __shfl_xor(lsum, 16, 64);
  lsum += __shfl_xor(lsum, 32, 64);
  const float m2 = m + __logf(lsum);

  // ---- pass 2: normalize, store attn, inline PV ----
  const int srcA = lr + ((lk & 1) << 5);
  const int srcB = srcA + 16;
  const bool hi = lk >= 2;
  f32x4 cacc[4] = {};
  LK(kA, 0)
  for (int t = 0; t < 32; t += 2) {
    LK(kB, t + 1)
    P2(kA, t)
    LK(kA, (t + 2) & 31)
    P2(kB, t + 1)
  }

  // ctx write: lane (lr,lk) holds ctx[q=q0w+lk*4+r][d=dt*16+lr]
#pragma unroll
  for (int dt = 0; dt < 4; ++dt)
#pragma unroll
    for (int r = 0; r < 4; ++r)
      ctx[(size_t)(b * S_LEN + q0w + lk * 4 + r) * DM + h * HD + dt * 16 + lr] =
          f2bf(cacc[dt][r]);
}

// residual + LayerNorm: out = LN(pre + Qin) * gamma + beta, rows of 1024
__global__ __launch_bounds__(256) void ln_kernel(const float* __restrict__ pre,
                                                 const float* __restrict__ Qin,
                                                 const float* __restrict__ gamma,
                                                 const float* __restrict__ beta,
                                                 float* __restrict__ out) {
  __shared__ float red[4];
  const int row = blockIdx.x;
  const int tid = threadIdx.x;
  const int wv = tid >> 6, l = tid & 63;
  const float4 a = reinterpret_cast<const float4*>(pre + (size_t)row * DM)[tid];
  const float4 q = reinterpret_cast<const float4*>(Qin + (size_t)row * DM)[tid];
  float x0 = a.x + q.x, x1 = a.y + q.y, x2 = a.z + q.z, x3 = a.w + q.w;
  float s = x0 + x1 + x2 + x3;
#pragma unroll
  for (int off = 32; off >= 1; off >>= 1) s += __shfl_xor(s, off, 64);
  if (l == 0) red[wv] = s;
  __syncthreads();
  float mean = (red[0] + red[1] + red[2] + red[3]) * (1.0f / 1024.0f);
  __syncthreads();
  float d0 = x0 - mean, d1 = x1 - mean, d2 = x2 - mean, d3 = x3 - mean;
  float s2 = d0 * d0 + d1 * d1 + d2 * d2 + d3 * d3;
#pragma unroll
  for (int off = 32; off >= 1; off >>= 1) s2 += __shfl_xor(s2, off, 64);
  if (l == 0) red[wv] = s2;
  __syncthreads();
  float var = (red[0] + red[1] + red[2] + red[3]) * (1.0f / 1024.0f);
  float rstd = rsqrtf(var + 1e-5f);
  const float4 g = reinterpret_cast<const float4*>(gamma)[tid];
  const float4 bt = reinterpret_cast<const float4*>(beta)[tid];
  float4 o;
  o.x = d0 * rstd * g.x + bt.x;
  o.y = d1 * rstd * g.y + bt.y;
  o.z = d2 * rstd * g.z + bt.z;
  o.w = d3 * rstd * g.w + bt.w;
  reinterpret_cast<float4*>(out + (size_t)row * DM)[tid] = o;
}

extern "C" void kernel_launch(void* const* d_in, const int* in_sizes, int n_in,
                              void* d_out, int out_size, void* d_ws, size_t ws_size,
                              hipStream_t stream) {
  const float* Qi = (const float*)d_in[0];
  const float* Ki = (const float*)d_in[1];
  const float* Vi = (const float*)d_in[2];
  const unsigned char* mask = (const unsigned char*)d_in[3];
  const float* Wq = (const float*)d_in[4];
  const float* bq = (const float*)d_in[5];
  const float* Wk = (const float*)d_in[6];
  const float* bk = (const float*)d_in[7];
  const float* Wv = (const float*)d_in[8];
  const float* bv = (const float*)d_in[9];
  const float* Wo = (const float*)d_in[10];
  const float* bo = (const float*)d_in[11];
  const float* gamma = (const float*)d_in[12];
  const float* beta = (const float*)d_in[13];

  char* ws = (char*)d_ws;
  unsigned short* Qb = (unsigned short*)(ws);            // [4096][1024] bf16
  unsigned short* Kb = Qb + 4194304;
  unsigned short* Vb = Qb + 2 * 4194304;
  unsigned short* Wtq = (unsigned short*)(ws + 25165824);  // [n][k] bf16 x4
  unsigned short* Wtk = Wtq + 1048576;
  unsigned short* Wtv = Wtq + 2 * 1048576;
  unsigned short* Wto = Wtq + 3 * 1048576;
  unsigned short* Qhd = (unsigned short*)(ws + 33554432);  // [B,H,S,64] bf16
  unsigned short* Khd = (unsigned short*)(ws + 41943040);  // [B,H,S,64] bf16
  unsigned short* Vtd = (unsigned short*)(ws + 50331648);  // [B,H,64,S] bf16
  unsigned short* ctx = (unsigned short*)(ws);             // reuse Qb region
  float* preLN = (float*)(ws + 8388608);                   // reuse Kb/Vb region

  float* out0 = (float*)d_out;
  float* attn = out0 + 4194304;

  cvt_kernel<<<4096, 256, 0, stream>>>(Qi, Qb);
  cvt_kernel<<<4096, 256, 0, stream>>>(Ki, Kb);
  cvt_kernel<<<4096, 256, 0, stream>>>(Vi, Vb);
  dim3 tg(32, 32);
  wtrans_kernel<<<tg, 256, 0, stream>>>(Wq, Wtq);
  wtrans_kernel<<<tg, 256, 0, stream>>>(Wk, Wtk);
  wtrans_kernel<<<tg, 256, 0, stream>>>(Wv, Wtv);
  wtrans_kernel<<<tg, 256, 0, stream>>>(Wo, Wto);
  dim3 gg(32, 8);
  gemm128<0><<<gg, 256, 0, stream>>>(Qb, Wtq, bq, Qhd);
  gemm128<0><<<gg, 256, 0, stream>>>(Kb, Wtk, bk, Khd);
  gemm128<1><<<gg, 256, 0, stream>>>(Vb, Wtv, bv, Vtd);
  dim3 ag(16, 32);
  attn2_kernel<<<ag, 512, 0, stream>>>(Qhd, Khd, Vtd, mask, attn, ctx);
  gemm128<2><<<gg, 256, 0, stream>>>(ctx, Wto, bo, preLN);
  ln_kernel<<<4096, 256, 0, stream>>>(preLN, Qi, gamma, beta, out0);
}

// Round 7
// 424.062 us; speedup vs baseline: 1.2056x; 1.2056x over previous
//
#include <hip/hip_runtime.h>
#include <hip/hip_bf16.h>

#define S_LEN 2048
#define NH 16
#define HD 64
#define DM 1024

typedef float f32x4 __attribute__((ext_vector_type(4)));
typedef unsigned u32x4 __attribute__((ext_vector_type(4)));
typedef __bf16 bf16x8 __attribute__((ext_vector_type(8)));

__device__ __forceinline__ unsigned short f2bf(float f) {
  union { float f; unsigned u; } v; v.f = f;
  unsigned r = v.u + 0x7fffu + ((v.u >> 16) & 1u);
  return (unsigned short)(r >> 16);
}

__device__ __forceinline__ unsigned pack2bf(float lo, float hi) {
  return (unsigned)f2bf(lo) | ((unsigned)f2bf(hi) << 16);
}

__device__ __forceinline__ void load_lds16(const void* g, void* l) {
  __builtin_amdgcn_global_load_lds((const __attribute__((address_space(1))) void*)g,
                                   (__attribute__((address_space(3))) void*)l, 16, 0, 0);
}

// fp32 -> bf16 rowmajor convert (4 elems/thread)
__global__ __launch_bounds__(256) void cvt_kernel(const float* __restrict__ in,
                                                  unsigned short* __restrict__ out) {
  int i = blockIdx.x * 256 + threadIdx.x;
  float4 v = reinterpret_cast<const float4*>(in)[i];
  ushort4 o;
  o.x = f2bf(v.x); o.y = f2bf(v.y); o.z = f2bf(v.z); o.w = f2bf(v.w);
  reinterpret_cast<ushort4*>(out)[i] = o;
}

// W [1024][1024] fp32 -> Wt [n][k] bf16 (transpose + convert)
__global__ __launch_bounds__(256) void wtrans_kernel(const float* __restrict__ W,
                                                     unsigned short* __restrict__ Wt) {
  __shared__ float t[32][33];
  int bx = blockIdx.x * 32;  // n base
  int by = blockIdx.y * 32;  // k base
  int tx = threadIdx.x & 31, ty = threadIdx.x >> 5;
  for (int i = ty; i < 32; i += 8) t[i][tx] = W[(size_t)(by + i) * DM + bx + tx];
  __syncthreads();
  for (int i = ty; i < 32; i += 8) Wt[(size_t)(bx + i) * DM + by + tx] = f2bf(t[tx][i]);
}

// C = A[4096x1024] @ Bt[1024x1024]^T + bias.  128x128 tile, BK=32, 4 waves.
// MODE 0: bf16 head-major out [B,H,S,64]; MODE 1: bf16 transposed [B,H,64,S]; MODE 2: fp32 rowmajor.
template <int MODE>
__global__ __launch_bounds__(256) void gemm128(const unsigned short* __restrict__ A,
                                               const unsigned short* __restrict__ Bt,
                                               const float* __restrict__ bias,
                                               void* __restrict__ outp) {
  constexpr int K = 1024;
  constexpr int N = 1024;
  __shared__ unsigned short Al[128 * 32];
  __shared__ unsigned short Bl[128 * 32];
  const int tid = threadIdx.x;
  const int w = tid >> 6, l = tid & 63;
  const int m0 = blockIdx.x * 128, n0 = blockIdx.y * 128;
  const int wr = (w >> 1) * 64, wc = (w & 1) * 64;
  const int lr = l & 15, lk = l >> 4;
  f32x4 acc[4][4] = {};
  for (int kt = 0; kt < K; kt += 32) {
#pragma unroll
    for (int i = 0; i < 2; ++i) {
      int seg = i * 256 + tid;
      int row = seg >> 2, ks = (seg & 3) * 8;
      load_lds16(A + (size_t)(m0 + row) * K + kt + ks, Al + seg * 8);
      load_lds16(Bt + (size_t)(n0 + row) * K + kt + ks, Bl + seg * 8);
    }
    __syncthreads();
    bf16x8 af[4], bfr[4];
#pragma unroll
    for (int t = 0; t < 4; ++t) af[t] = *(const bf16x8*)(Al + (wr + t * 16 + lr) * 32 + lk * 8);
#pragma unroll
    for (int t = 0; t < 4; ++t) bfr[t] = *(const bf16x8*)(Bl + (wc + t * 16 + lr) * 32 + lk * 8);
#pragma unroll
    for (int i = 0; i < 4; ++i)
#pragma unroll
      for (int j = 0; j < 4; ++j)
        acc[i][j] = __builtin_amdgcn_mfma_f32_16x16x32_bf16(af[i], bfr[j], acc[i][j], 0, 0, 0);
    __syncthreads();
  }
  const int drow = lk * 4, dcol = lr;
  if (MODE == 2) {
    float* C = (float*)outp;
#pragma unroll
    for (int i = 0; i < 4; ++i)
#pragma unroll
      for (int j = 0; j < 4; ++j) {
        int n = n0 + wc + j * 16 + dcol;
        float bv = bias[n];
#pragma unroll
        for (int r = 0; r < 4; ++r) {
          int m = m0 + wr + i * 16 + drow + r;
          C[(size_t)m * N + n] = acc[i][j][r] + bv;
        }
      }
  } else if (MODE == 0) {
    unsigned short* C = (unsigned short*)outp;
#pragma unroll
    for (int i = 0; i < 4; ++i)
#pragma unroll
      for (int j = 0; j < 4; ++j) {
        int n = n0 + wc + j * 16 + dcol;
        float bv = bias[n];
        int h = n >> 6, d = n & 63;
#pragma unroll
        for (int r = 0; r < 4; ++r) {
          int m = m0 + wr + i * 16 + drow + r;
          int b = m >> 11, s = m & 2047;
          C[((size_t)(b * NH + h) * S_LEN + s) * HD + d] = f2bf(acc[i][j][r] + bv);
        }
      }
  } else {  // MODE 1: V transposed [B,H,64,S]
    unsigned short* C = (unsigned short*)outp;
#pragma unroll
    for (int i = 0; i < 4; ++i) {
      int m = m0 + wr + i * 16 + drow;  // rows m..m+3 same b (16-aligned)
      int b = m >> 11, s = m & 2047;
#pragma unroll
      for (int j = 0; j < 4; ++j) {
        int n = n0 + wc + j * 16 + dcol;
        float bv = bias[n];
        int h = n >> 6, d = n & 63;
        ushort4 o;
        o.x = f2bf(acc[i][j][0] + bv);
        o.y = f2bf(acc[i][j][1] + bv);
        o.z = f2bf(acc[i][j][2] + bv);
        o.w = f2bf(acc[i][j][3] + bv);
        *reinterpret_cast<ushort4*>(C + ((size_t)(b * NH + h) * HD + d) * S_LEN + s) = o;
      }
    }
  }
}

// ---------------------------------------------------------------------------
// Two-pass flash attention, LDS-staged K/V shared by all 8 waves of the block.
// Block = 512 thr; wave w owns q-rows [q0w,q0w+16) for the full k=2048.
// KVBLK = 128 k per tile; K tile [128][64]bf16 = 16 KB, V tile [64][128]bf16 =
// 16 KB, double-buffered (64 KB LDS). Staging via global_load_lds with the
// both-sides XOR swizzle (byte ^= (row&7)<<4): linear LDS dest, pre-swizzled
// global source, same XOR on ds_read -> 2-way conflicts (free).
// 2-phase loop: issue STAGE(next) -> compute(cur) -> __syncthreads (drains
// vmcnt) -> swap. Swapped-operand QK^T (A=K,B=Q): lane (lr,lk) holds
// S[k=st*16+lk*4+r][q=q0w+lr]; softmax is wave-local.
// ---------------------------------------------------------------------------
#define STAGE_K(T, B)                                                          \
  _Pragma("unroll") for (int i = 0; i < 2; ++i) {                              \
    int s = i * 512 + tid;                                                     \
    int row = s >> 3, cb = (s & 7) * 16;                                       \
    load_lds16((const char*)Kbh + (size_t)((T) * 128 + row) * 128 +            \
                   (cb ^ ((row & 7) << 4)),                                    \
               (char*)ldsK4[B] + s * 16);                                      \
  }

#define STAGE_V(T, B)                                                          \
  _Pragma("unroll") for (int i = 0; i < 2; ++i) {                              \
    int s = i * 512 + tid;                                                     \
    int row = s >> 4, cb = (s & 15) * 16;                                      \
    load_lds16((const char*)Vbh + (size_t)row * 4096 + (T) * 256 +             \
                   (cb ^ ((row & 7) << 4)),                                    \
               (char*)ldsV4[B] + s * 16);                                      \
  }

#define QKT_LDS(KPTR)                                                          \
  _Pragma("unroll") for (int st = 0; st < 8; ++st) {                           \
    const char* rp = (KPTR) + (st * 16 + lr) * 128;                            \
    bf16x8 k0 = *(const bf16x8*)(rp + a0);                                     \
    bf16x8 k1 = *(const bf16x8*)(rp + (a0 ^ 64));                              \
    f32x4 a = {};                                                              \
    a = __builtin_amdgcn_mfma_f32_16x16x32_bf16(k0, qf0, a, 0, 0, 0);          \
    a = __builtin_amdgcn_mfma_f32_16x16x32_bf16(k1, qf1, a, 0, 0, 0);          \
    acc[st] = a;                                                               \
  }

#define MASKADJ8(T)                                                            \
  _Pragma("unroll") for (int st = 0; st < 8; ++st) {                           \
    uchar4 m4 = *(const uchar4*)(mrow + (T) * 128 + st * 16 + lk * 4);         \
    if (m4.x) acc[st][0] = -8e9f;                                              \
    if (m4.y) acc[st][1] = -8e9f;                                              \
    if (m4.z) acc[st][2] = -8e9f;                                              \
    if (m4.w) acc[st][3] = -8e9f;                                              \
  }

__global__ __launch_bounds__(512, 4) void attn3_kernel(const unsigned short* __restrict__ Qh,
                                                       const unsigned short* __restrict__ Kh,
                                                       const unsigned short* __restrict__ Vt,
                                                       const unsigned char* __restrict__ mask,
                                                       float* __restrict__ attn_out,
                                                       unsigned short* __restrict__ ctx) {
  __shared__ f32x4 ldsK4[2][1024];  // 2 x 16 KB
  __shared__ f32x4 ldsV4[2][1024];  // 2 x 16 KB
  const int tid = threadIdx.x;
  const int w = tid >> 6, l = tid & 63;
  const int lr = l & 15, lk = l >> 4;
  // XCD-clustered decode: the 16 q-tile blocks of one bh share L%8 -> one XCD L2
  const int L = blockIdx.x;
  const int g = L & 7, j = L >> 3;
  const int bh = g * 4 + (j & 3);
  const int qt = j >> 2;
  const int q0w = qt * 128 + w * 16;
  const int b = bh >> 4, h = bh & 15;
  const unsigned short* Qbh = Qh + (size_t)bh * S_LEN * HD;
  const unsigned short* Kbh = Kh + (size_t)bh * S_LEN * HD;
  const unsigned short* Vbh = Vt + (size_t)bh * HD * S_LEN;
  const unsigned char* mrow = mask + (size_t)b * S_LEN * S_LEN + (size_t)(q0w + lr) * S_LEN;
  float* arow = attn_out + ((size_t)bh * S_LEN + q0w + lr) * S_LEN;

  bf16x8 qf0 = *(const bf16x8*)(Qbh + (q0w + lr) * HD + lk * 8);
  bf16x8 qf1 = *(const bf16x8*)(Qbh + (q0w + lr) * HD + 32 + lk * 8);

  const int sw = (lr & 7) << 4;
  const int a0 = (lk * 16) ^ sw;
  const float sc = 0.125f;  // 1/sqrt(64)

  float m = -3e38f, lsum = 0.f;
  unsigned maskbits = 0;
  int buf = 0;
  f32x4 acc[8];

  // ---- pass 1: online max/sum ----
  STAGE_K(0, 0)
  __syncthreads();
  for (int t = 0; t < 16; ++t) {
    if (t < 15) STAGE_K(t + 1, buf ^ 1)
    int anymask;
    {
      const unsigned char* mp = mrow + t * 128 + lk * 32;
      u32x4 v0 = __builtin_nontemporal_load((const u32x4*)mp);
      u32x4 v1 = __builtin_nontemporal_load((const u32x4*)(mp + 16));
      unsigned orv = v0.x | v0.y | v0.z | v0.w | v1.x | v1.y | v1.z | v1.w;
      anymask = __any(orv != 0);
    }
    const char* Kp = (const char*)ldsK4[buf];
    QKT_LDS(Kp)
    if (anymask) {
      maskbits |= 1u << t;
      MASKADJ8(t)
    }
    float tm = -3e38f;
#pragma unroll
    for (int st = 0; st < 8; ++st)
#pragma unroll
      for (int r = 0; r < 4; ++r) {
        float v = acc[st][r] * sc;
        acc[st][r] = v;
        tm = fmaxf(tm, v);
      }
    tm = fmaxf(tm, __shfl_xor(tm, 16, 64));
    tm = fmaxf(tm, __shfl_xor(tm, 32, 64));
    float mn = fmaxf(m, tm);
    float ts = 0.f;
#pragma unroll
    for (int st = 0; st < 8; ++st)
#pragma unroll
      for (int r = 0; r < 4; ++r) ts += __expf(acc[st][r] - mn);
    lsum = lsum * __expf(m - mn) + ts;
    m = mn;
    __syncthreads();
    buf ^= 1;
  }
  lsum += __shfl_xor(lsum, 16, 64);
  lsum += __shfl_xor(lsum, 32, 64);
  const float m2 = m + __logf(lsum);

  // ---- pass 2: normalized attn store + PV ----
  const int srcA = lr + ((lk & 1) << 5);
  const int srcB = srcA + 16;
  const bool hi = lk >= 2;
  f32x4 cacc[4] = {};
  buf = 0;
  STAGE_K(0, 0)
  STAGE_V(0, 0)
  __syncthreads();
  for (int t = 0; t < 16; ++t) {
    if (t < 15) {
      STAGE_K(t + 1, buf ^ 1)
      STAGE_V(t + 1, buf ^ 1)
    }
    const char* Kp = (const char*)ldsK4[buf];
    const char* Vp = (const char*)ldsV4[buf];
    QKT_LDS(Kp)
    if (maskbits & (1u << t)) {
      MASKADJ8(t)
    }
#pragma unroll
    for (int ks = 0; ks < 4; ++ks) {
      unsigned e0, e1, o0, o1;
      {
        int st = 2 * ks;
        f32x4 p;
        p.x = __expf(acc[st][0] * sc - m2);
        p.y = __expf(acc[st][1] * sc - m2);
        p.z = __expf(acc[st][2] * sc - m2);
        p.w = __expf(acc[st][3] * sc - m2);
        __builtin_nontemporal_store(p, (f32x4*)(arow + t * 128 + st * 16 + lk * 4));
        e0 = pack2bf(p.x, p.y);
        e1 = pack2bf(p.z, p.w);
        st = 2 * ks + 1;
        p.x = __expf(acc[st][0] * sc - m2);
        p.y = __expf(acc[st][1] * sc - m2);
        p.z = __expf(acc[st][2] * sc - m2);
        p.w = __expf(acc[st][3] * sc - m2);
        __builtin_nontemporal_store(p, (f32x4*)(arow + t * 128 + st * 16 + lk * 4));
        o0 = pack2bf(p.x, p.y);
        o1 = pack2bf(p.z, p.w);
      }
      unsigned x0a = __shfl(e0, srcA, 64), x1a = __shfl(e1, srcA, 64);
      unsigned x2a = __shfl(e0, srcB, 64), x3a = __shfl(e1, srcB, 64);
      unsigned x0b = __shfl(o0, srcA, 64), x1b = __shfl(o1, srcA, 64);
      unsigned x2b = __shfl(o0, srcB, 64), x3b = __shfl(o1, srcB, 64);
      union { unsigned u[4]; bf16x8 v; } af;
      af.u[0] = hi ? x0b : x0a;
      af.u[1] = hi ? x1b : x1a;
      af.u[2] = hi ? x2b : x2a;
      af.u[3] = hi ? x3b : x3a;
#pragma unroll
      for (int dt = 0; dt < 4; ++dt) {
        bf16x8 vb = *(const bf16x8*)(Vp + (dt * 16 + lr) * 256 + ((ks * 64) ^ a0));
        cacc[dt] = __builtin_amdgcn_mfma_f32_16x16x32_bf16(af.v, vb, cacc[dt], 0, 0, 0);
      }
    }
    __syncthreads();
    buf ^= 1;
  }

  // ctx write: lane (lr,lk) holds ctx[q=q0w+lk*4+r][d=dt*16+lr]
#pragma unroll
  for (int dt = 0; dt < 4; ++dt)
#pragma unroll
    for (int r = 0; r < 4; ++r)
      ctx[(size_t)(b * S_LEN + q0w + lk * 4 + r) * DM + h * HD + dt * 16 + lr] =
          f2bf(cacc[dt][r]);
}

// residual + LayerNorm: out = LN(pre + Qin) * gamma + beta, rows of 1024
__global__ __launch_bounds__(256) void ln_kernel(const float* __restrict__ pre,
                                                 const float* __restrict__ Qin,
                                                 const float* __restrict__ gamma,
                                                 const float* __restrict__ beta,
                                                 float* __restrict__ out) {
  __shared__ float red[4];
  const int row = blockIdx.x;
  const int tid = threadIdx.x;
  const int wv = tid >> 6, l = tid & 63;
  const float4 a = reinterpret_cast<const float4*>(pre + (size_t)row * DM)[tid];
  const float4 q = reinterpret_cast<const float4*>(Qin + (size_t)row * DM)[tid];
  float x0 = a.x + q.x, x1 = a.y + q.y, x2 = a.z + q.z, x3 = a.w + q.w;
  float s = x0 + x1 + x2 + x3;
#pragma unroll
  for (int off = 32; off >= 1; off >>= 1) s += __shfl_xor(s, off, 64);
  if (l == 0) red[wv] = s;
  __syncthreads();
  float mean = (red[0] + red[1] + red[2] + red[3]) * (1.0f / 1024.0f);
  __syncthreads();
  float d0 = x0 - mean, d1 = x1 - mean, d2 = x2 - mean, d3 = x3 - mean;
  float s2 = d0 * d0 + d1 * d1 + d2 * d2 + d3 * d3;
#pragma unroll
  for (int off = 32; off >= 1; off >>= 1) s2 += __shfl_xor(s2, off, 64);
  if (l == 0) red[wv] = s2;
  __syncthreads();
  float var = (red[0] + red[1] + red[2] + red[3]) * (1.0f / 1024.0f);
  float rstd = rsqrtf(var + 1e-5f);
  const float4 g = reinterpret_cast<const float4*>(gamma)[tid];
  const float4 bt = reinterpret_cast<const float4*>(beta)[tid];
  float4 o;
  o.x = d0 * rstd * g.x + bt.x;
  o.y = d1 * rstd * g.y + bt.y;
  o.z = d2 * rstd * g.z + bt.z;
  o.w = d3 * rstd * g.w + bt.w;
  reinterpret_cast<float4*>(out + (size_t)row * DM)[tid] = o;
}

extern "C" void kernel_launch(void* const* d_in, const int* in_sizes, int n_in,
                              void* d_out, int out_size, void* d_ws, size_t ws_size,
                              hipStream_t stream) {
  const float* Qi = (const float*)d_in[0];
  const float* Ki = (const float*)d_in[1];
  const float* Vi = (const float*)d_in[2];
  const unsigned char* mask = (const unsigned char*)d_in[3];
  const float* Wq = (const float*)d_in[4];
  const float* bq = (const float*)d_in[5];
  const float* Wk = (const float*)d_in[6];
  const float* bk = (const float*)d_in[7];
  const float* Wv = (const float*)d_in[8];
  const float* bv = (const float*)d_in[9];
  const float* Wo = (const float*)d_in[10];
  const float* bo = (const float*)d_in[11];
  const float* gamma = (const float*)d_in[12];
  const float* beta = (const float*)d_in[13];

  char* ws = (char*)d_ws;
  unsigned short* Qb = (unsigned short*)(ws);            // [4096][1024] bf16
  unsigned short* Kb = Qb + 4194304;
  unsigned short* Vb = Qb + 2 * 4194304;
  unsigned short* Wtq = (unsigned short*)(ws + 25165824);  // [n][k] bf16 x4
  unsigned short* Wtk = Wtq + 1048576;
  unsigned short* Wtv = Wtq + 2 * 1048576;
  unsigned short* Wto = Wtq + 3 * 1048576;
  unsigned short* Qhd = (unsigned short*)(ws + 33554432);  // [B,H,S,64] bf16
  unsigned short* Khd = (unsigned short*)(ws + 41943040);  // [B,H,S,64] bf16
  unsigned short* Vtd = (unsigned short*)(ws + 50331648);  // [B,H,64,S] bf16
  unsigned short* ctx = (unsigned short*)(ws);             // reuse Qb region
  float* preLN = (float*)(ws + 8388608);                   // reuse Kb/Vb region

  float* out0 = (float*)d_out;
  float* attn = out0 + 4194304;

  cvt_kernel<<<4096, 256, 0, stream>>>(Qi, Qb);
  cvt_kernel<<<4096, 256, 0, stream>>>(Ki, Kb);
  cvt_kernel<<<4096, 256, 0, stream>>>(Vi, Vb);
  dim3 tg(32, 32);
  wtrans_kernel<<<tg, 256, 0, stream>>>(Wq, Wtq);
  wtrans_kernel<<<tg, 256, 0, stream>>>(Wk, Wtk);
  wtrans_kernel<<<tg, 256, 0, stream>>>(Wv, Wtv);
  wtrans_kernel<<<tg, 256, 0, stream>>>(Wo, Wto);
  dim3 gg(32, 8);
  gemm128<0><<<gg, 256, 0, stream>>>(Qb, Wtq, bq, Qhd);
  gemm128<0><<<gg, 256, 0, stream>>>(Kb, Wtk, bk, Khd);
  gemm128<1><<<gg, 256, 0, stream>>>(Vb, Wtv, bv, Vtd);
  attn3_kernel<<<512, 512, 0, stream>>>(Qhd, Khd, Vtd, mask, attn, ctx);
  gemm128<2><<<gg, 256, 0, stream>>>(ctx, Wto, bo, preLN);
  ln_kernel<<<4096, 256, 0, stream>>>(preLN, Qi, gamma, beta, out0);
}